// Round 2
// baseline (1539.707 us; speedup 1.0000x reference)
//
#include <hip/hip_runtime.h>
#include <hip/hip_bf16.h>
#include <hip/hip_fp16.h>

#define VOCAB 5000
#define EMB 128
#define H1D 128
#define H2D 64
#define QD 64
#define TDIM 256
#define BDIM 512
#define LTEXT 30
#define LSTEPS 29

typedef __attribute__((ext_vector_type(4))) float f32x4;
typedef __attribute__((ext_vector_type(8))) _Float16 f16x8;
typedef __attribute__((ext_vector_type(2))) _Float16 h2v;

// ---- workspace layout (bytes) ----
#define OFF_WOUT  0u                    // 5000*128 fp16 = 1,280,000
#define OFF_W1H   0x140000u             // 512*320 fp16  =   327,680
#define OFF_W2H   (OFF_W1H + 512u*320u*2u)
#define OFF_WQH   (OFF_W2H + 256u*192u*2u)
#define OFF_B1    (OFF_WQH + 64u*64u*2u)
#define OFF_B2    (OFF_B1 + 512u*4u)
#define OFF_H2CTX 0x1B0000u             // 14848*128 fp16 = 3,801,088

__device__ __forceinline__ float sigmoidf_(float x) {
    return __builtin_amdgcn_rcpf(1.0f + __expf(-x));
}

__device__ __forceinline__ float tanh_fast(float x) {
    // 1 - 2/(e^{2x}+1): monotone, saturates correctly at +/-1, no libm branches
    float e = __expf(2.0f * x);
    return 1.0f - 2.0f * __builtin_amdgcn_rcpf(e + 1.0f);
}

__device__ __forceinline__ float dot8(f16x8 w, f16x8 u, float acc) {
    union U8 { f16x8 v; h2v h[4]; };
    U8 W; W.v = w; U8 X; X.v = u;
#if __has_builtin(__builtin_amdgcn_fdot2)
    acc = __builtin_amdgcn_fdot2(W.h[0], X.h[0], acc, false);
    acc = __builtin_amdgcn_fdot2(W.h[1], X.h[1], acc, false);
    acc = __builtin_amdgcn_fdot2(W.h[2], X.h[2], acc, false);
    acc = __builtin_amdgcn_fdot2(W.h[3], X.h[3], acc, false);
#else
    #pragma unroll
    for (int i = 0; i < 8; ++i) acc += (float)w[i] * (float)u[i];
#endif
    return acc;
}

// Load an f16x8 from global and pin its 4 dwords into arch VGPRs so the
// compiler can neither rematerialize the load inside the step loop nor
// park the value in AGPRs.
__device__ __forceinline__ f16x8 load_pin(const f16x8* p) {
    union WU { f16x8 h; float f[4]; } u;
    u.h = *p;
    asm volatile("" : "+v"(u.f[0]), "+v"(u.f[1]), "+v"(u.f[2]), "+v"(u.f[3]));
    return u.h;
}

// ---------------------------------------------------------------------------
// Prep kernels: pack weights to fp16, fold biases. (unchanged)
// ---------------------------------------------------------------------------
__global__ void k_cvt_f16(const float* __restrict__ W, _Float16* __restrict__ Wh, int n) {
    int i = blockIdx.x * 256 + threadIdx.x;
    if (i < n) Wh[i] = (_Float16)W[i];
}

__global__ void k_prep_w1(const float* __restrict__ Wih1, const float* __restrict__ Whh1,
                          const float* __restrict__ bih1, const float* __restrict__ bhh1,
                          _Float16* __restrict__ W1h, float* __restrict__ bias1) {
    int g = blockIdx.x;          // 512
    int k = threadIdx.x;         // 320
    float v = (k < 192) ? Wih1[g * 192 + k] : Whh1[g * 128 + (k - 192)];
    W1h[g * 320 + k] = (_Float16)v;
    if (k == 0) bias1[g] = bih1[g] + bhh1[g];
}

__global__ void k_prep_w2(const float* __restrict__ Wih2, const float* __restrict__ Whh2,
                          const float* __restrict__ bih2, const float* __restrict__ bhh2,
                          _Float16* __restrict__ W2h, float* __restrict__ bias2) {
    int g = blockIdx.x;          // 256
    int k = threadIdx.x;         // 192
    float v = (k < 128) ? Wih2[g * 128 + k] : Whh2[g * 64 + (k - 128)];
    W2h[g * 192 + k] = (_Float16)v;
    if (k == 0) bias2[g] = bih2[g] + bhh2[g];
}

// ---------------------------------------------------------------------------
// Kernel A v4: 512 blocks x 1024 threads, 1 row/block, 2 blocks/CU (32 waves).
//  - W1 half-rows (80 VGPR) + W2 quarter-rows (24 VGPR) pinned in registers
//  - key slot-major in LDS (conflict-free b128), valT swizzled (free)
//  - split-K partials combined with adjacent-lane shfl (no extra barriers)
//  - single-barrier softmax (per-wave max + rescaled sums)
//  - u buffer [x|ctx|h1|h2] shared by g1 (0..319) and g2 (192..383)
// ---------------------------------------------------------------------------
__global__ __launch_bounds__(1024, 8) void k_recurrent(
    const float* __restrict__ key, const float* __restrict__ values,
    const float* __restrict__ mask, const int* __restrict__ text,
    const float* __restrict__ emb,
    const _Float16* __restrict__ W1h, const float* __restrict__ bias1,
    const _Float16* __restrict__ W2h, const float* __restrict__ bias2,
    const _Float16* __restrict__ Wqh, const float* __restrict__ bq,
    _Float16* __restrict__ h2ctx)
{
    __shared__ alignas(16) _Float16 s_key[8 * 256 * 8];   // [slot][t][8] 32 KB
    __shared__ alignas(16) _Float16 s_valT[64 * 256];     // [v][t] slot^=(v&31) 32 KB
    __shared__ alignas(16) _Float16 s_Wq[8 * 64 * 8];     // [slot][qj][8] 8 KB
    __shared__ alignas(16) _Float16 s_u16[384];           // [x128|ctx64|h1 128|h2 64]
    __shared__ alignas(16) _Float16 s_q16[64];
    __shared__ alignas(16) _Float16 s_ma16[256];
    __shared__ float s_g1[512];
    __shared__ float s_g2[256];
    __shared__ float s_redM[4], s_redA[4], s_redB[4];
    __shared__ int   s_tok[LSTEPS];

    const int tid = threadIdx.x;
    const int b = blockIdx.x;

    const int g1gate = tid >> 1, g1half = tid & 1;
    const int g2gate = tid >> 2, g2q = tid & 3;

    // ---- weights into pinned registers ----
    f16x8 w1h[20];
    {
        const f16x8* p = (const f16x8*)(W1h + (size_t)g1gate * 320 + g1half * 160);
        #pragma unroll
        for (int c = 0; c < 20; ++c) w1h[c] = load_pin(p + c);
    }
    f16x8 w2q[6];
    {
        const f16x8* p = (const f16x8*)(W2h + (size_t)g2gate * 192 + g2q * 48);
        #pragma unroll
        for (int c = 0; c < 6; ++c) w2q[c] = load_pin(p + c);
    }
    float b1r = bias1[g1gate]; if (g1half) b1r = 0.f;
    float b2r = bias2[g2gate]; if (g2q) b2r = 0.f;
    const float bqr  = (tid < 64)  ? bq[tid] : 0.f;
    const float mreg = (tid < 256) ? mask[(size_t)b * TDIM + tid] : 0.f;

    // ---- one-time preload ----
    if (tid < LSTEPS) s_tok[tid] = text[b * LTEXT + tid];
    if (tid < 128)    s_u16[tid] = (_Float16)emb[(size_t)text[b * LTEXT] * EMB + tid];
    if (tid >= 128 && tid < 384) s_u16[tid] = (_Float16)0.f;   // ctx, h1, h2 = 0
    if (tid < 512) {                                           // Wq slot-major
        int qj = tid >> 3, c = tid & 7;
        f16x8 w = *(const f16x8*)(Wqh + (qj << 6) + (c << 3));
        *(f16x8*)&s_Wq[(c << 9) + (qj << 3)] = w;
    }
    // key/values -> LDS fp16 (coalesced: one wave reads one t's 256B)
    {
        const int k = tid & 63;
        const int tw = tid >> 6;          // 0..15
        #pragma unroll 4
        for (int it = 0; it < 16; ++it) {
            int t = tw + (it << 4);
            size_t g = ((size_t)t * BDIM + b) * QD + k;
            float kf = key[g];
            float vf = values[g];
            s_key[((k >> 3) << 11) + (t << 3) + (k & 7)] = (_Float16)kf;
            s_valT[(k << 8) + ((((t >> 3) ^ (k & 31))) << 3) + (t & 7)] = (_Float16)vf;
        }
    }

    float c1reg = 0.f;   // tid<128: c1[j=tid]
    float c2reg = 0.f;   // tid<64 : c2[j=tid]
    __syncthreads();

    #pragma unroll 1
    for (int t = 0; t < LSTEPS; ++t) {
        // issue next-step embedding load early (write late)
        float xpref = 0.f;
        const bool havepref = (t + 1 < LSTEPS) && (tid < 128);
        if (havepref) xpref = emb[(size_t)s_tok[t + 1] * EMB + tid];

        // ---- g1: (gate, K-half), weights in VGPRs, u broadcast from LDS ----
        {
            const f16x8* up = (const f16x8*)&s_u16[g1half * 160];
            float a = b1r;
            #pragma unroll
            for (int c = 0; c < 20; ++c) a = dot8(w1h[c], up[c], a);
            a += __shfl_down(a, 1);
            if (g1half == 0) s_g1[g1gate] = a;
        }
        __syncthreads();                                   // B1

        // ---- LSTM1 (128 units), c1 in register ----
        if (tid < 128) {
            float gi = s_g1[tid], gf = s_g1[128 + tid];
            float gg = s_g1[256 + tid], go = s_g1[384 + tid];
            float c = sigmoidf_(gf) * c1reg + sigmoidf_(gi) * tanh_fast(gg);
            c1reg = c;
            float h = sigmoidf_(go) * tanh_fast(c);
            s_u16[192 + tid] = (_Float16)h;
        }
        __syncthreads();                                   // B2

        // ---- g2: (gate, K-quarter) ----
        {
            const f16x8* vp = (const f16x8*)&s_u16[192 + g2q * 48];
            float a = b2r;
            #pragma unroll
            for (int c = 0; c < 6; ++c) a = dot8(w2q[c], vp[c], a);
            a += __shfl_down(a, 1);
            a += __shfl_down(a, 2);
            if (g2q == 0) s_g2[g2gate] = a;
        }
        __syncthreads();                                   // B3

        // ---- LSTM2 (64 units), c2 in register; store h2 ----
        if (tid < 64) {
            float gi = s_g2[tid], gf = s_g2[64 + tid];
            float gg = s_g2[128 + tid], go = s_g2[192 + tid];
            float c = sigmoidf_(gf) * c2reg + sigmoidf_(gi) * tanh_fast(gg);
            c2reg = c;
            float h = sigmoidf_(go) * tanh_fast(c);
            s_u16[320 + tid] = (_Float16)h;
            h2ctx[((size_t)b * LSTEPS + t) * 128 + tid] = (_Float16)h;
        }
        __syncthreads();                                   // B4

        // ---- q = Wq @ h2 + bq (slot-major LDS, conflict-free) ----
        if (tid < 64) {
            const f16x8* hv = (const f16x8*)&s_u16[320];
            float a = bqr;
            #pragma unroll
            for (int c = 0; c < 8; ++c) {
                f16x8 w = *(const f16x8*)&s_Wq[(c << 9) + (tid << 3)];
                a = dot8(w, hv[c], a);
            }
            s_q16[tid] = (_Float16)a;
        }
        __syncthreads();                                   // B5

        // ---- energy + per-wave softmax partials (single cross-wave combine) ----
        float e = 0.f, mw = 0.f, pexp = 0.f;
        if (tid < 256) {
            const f16x8* qv = (const f16x8*)&s_q16[0];
            #pragma unroll
            for (int j = 0; j < 8; ++j) {
                f16x8 kk = *(const f16x8*)&s_key[(j << 11) + (tid << 3)];
                e = dot8(kk, qv[j], e);
            }
            float m = e;
            #pragma unroll
            for (int off = 1; off < 64; off <<= 1) m = fmaxf(m, __shfl_xor(m, off));
            mw = m;
            pexp = __expf(e - mw);
            float mp = mreg * pexp;
            float sp = pexp, smp = mp;
            #pragma unroll
            for (int off = 1; off < 64; off <<= 1) {
                sp += __shfl_xor(sp, off);
                smp += __shfl_xor(smp, off);
            }
            if ((tid & 63) == 0) {
                int w = tid >> 6;
                s_redM[w] = mw; s_redA[w] = sp; s_redB[w] = smp;
            }
        }
        __syncthreads();                                   // B6

        if (tid < 256) {
            float m = fmaxf(fmaxf(s_redM[0], s_redM[1]), fmaxf(s_redM[2], s_redM[3]));
            float S1 = 0.f, S2 = 0.f;
            #pragma unroll
            for (int w = 0; w < 4; ++w) {
                float sc = __expf(s_redM[w] - m);
                S1 += s_redA[w] * sc;
                S2 += s_redB[w] * sc;
            }
            float scale = __expf(mw - m);
            float mp = mreg * pexp * scale;
            float denom = fmaxf(S2, 2e-30f * S1);
            s_ma16[tid] = (_Float16)(mp * __builtin_amdgcn_rcpf(denom));
        }
        __syncthreads();                                   // B7

        // ---- ctx: (v = tid>>3, chunk = tid&7), 8-lane shuffle combine ----
        float cacc = 0.f;
        if (tid < 512) {
            const int v = tid >> 3, ch = tid & 7;
            #pragma unroll
            for (int j = 0; j < 4; ++j) {
                int s = (ch << 2) + j;
                f16x8 vv = *(const f16x8*)&s_valT[(v << 8) + (((s ^ (v & 31))) << 3)];
                f16x8 ma = *(const f16x8*)&s_ma16[s << 3];
                cacc = dot8(vv, ma, cacc);
            }
            cacc += __shfl_down(cacc, 1);
            cacc += __shfl_down(cacc, 2);
            cacc += __shfl_down(cacc, 4);
        }
        if (havepref) s_u16[tid] = (_Float16)xpref;        // next-step x (g1 done at B1)
        if (tid < 512 && (tid & 7) == 0) {
            int v = tid >> 3;
            s_u16[128 + v] = (_Float16)cacc;
            h2ctx[((size_t)b * LSTEPS + t) * 128 + 64 + v] = (_Float16)cacc;
        }
        __syncthreads();                                   // B8
    }
}

// ---------------------------------------------------------------------------
// Kernel B: out = h2ctx @ W_out^T + b_out, fp16 MFMA 16x16x32.
// M = 14848, N = 5000, K = 128. 64x64 tile, 4 waves.
// Operands swapped so the accumulator reg-axis is the vocab axis ->
// coalesced float4 stores.
// ---------------------------------------------------------------------------
#define KP 136

__global__ __launch_bounds__(256, 4) void k_outproj(
    const _Float16* __restrict__ A,
    const _Float16* __restrict__ Bw,
    const float* __restrict__ b_out,
    float* __restrict__ out)
{
    __shared__ _Float16 As[64 * KP];
    __shared__ _Float16 Bs[64 * KP];
    const int tid = threadIdx.x;
    const int m0 = blockIdx.y * 64;
    const int v0 = blockIdx.x * 64;

    const uint4* Ag = (const uint4*)(A + (size_t)m0 * 128);
    uint4* AsU = (uint4*)As;
    #pragma unroll
    for (int i = 0; i < 4; ++i) {
        int fi = tid + 256 * i;
        int r = fi >> 4, c = fi & 15;
        AsU[r * 17 + c] = Ag[fi];
    }
    const uint4* Bg = (const uint4*)Bw;
    uint4* BsU = (uint4*)Bs;
    #pragma unroll
    for (int i = 0; i < 4; ++i) {
        int fi = tid + 256 * i;
        int r = fi >> 4, c = fi & 15;
        int v = v0 + r;
        uint4 val = make_uint4(0u, 0u, 0u, 0u);
        if (v < VOCAB) val = Bg[(size_t)v * 16 + c];
        BsU[r * 17 + c] = val;
    }
    __syncthreads();

    const int wv = tid >> 6, lane = tid & 63;
    const int fm = lane & 15, quad = lane >> 4;

    f32x4 acc[4];
    #pragma unroll
    for (int nt = 0; nt < 4; ++nt) acc[nt] = (f32x4){0.f, 0.f, 0.f, 0.f};

    #pragma unroll
    for (int kt = 0; kt < 4; ++kt) {
        f16x8 af = *(const f16x8*)&As[(16 * wv + fm) * KP + kt * 32 + quad * 8];
        #pragma unroll
        for (int nt = 0; nt < 4; ++nt) {
            f16x8 bf = *(const f16x8*)&Bs[(nt * 16 + fm) * KP + kt * 32 + quad * 8];
            // swapped: D[v-quad][m] so each lane's 4 acc regs are consecutive v
            acc[nt] = __builtin_amdgcn_mfma_f32_16x16x32_f16(bf, af, acc[nt], 0, 0, 0);
        }
    }

    const int rowm = m0 + 16 * wv + fm;
    #pragma unroll
    for (int nt = 0; nt < 4; ++nt) {
        int vb = v0 + nt * 16 + quad * 4;
        if (vb + 3 < VOCAB) {
            float4 bo = *(const float4*)&b_out[vb];
            float4 res;
            res.x = acc[nt][0] + bo.x;
            res.y = acc[nt][1] + bo.y;
            res.z = acc[nt][2] + bo.z;
            res.w = acc[nt][3] + bo.w;
            *(float4*)&out[(size_t)rowm * VOCAB + vb] = res;
        } else {
            #pragma unroll
            for (int r = 0; r < 4; ++r) {
                int v = vb + r;
                if (v < VOCAB) out[(size_t)rowm * VOCAB + v] = acc[nt][r] + b_out[v];
            }
        }
    }
}

extern "C" void kernel_launch(void* const* d_in, const int* in_sizes, int n_in,
                              void* d_out, int out_size, void* d_ws, size_t ws_size,
                              hipStream_t stream) {
    const float* key    = (const float*)d_in[0];
    const float* values = (const float*)d_in[1];
    const float* mask   = (const float*)d_in[2];
    const int*   text   = (const int*)d_in[3];
    const float* emb    = (const float*)d_in[4];
    const float* Wih1   = (const float*)d_in[5];
    const float* Whh1   = (const float*)d_in[6];
    const float* bih1   = (const float*)d_in[7];
    const float* bhh1   = (const float*)d_in[8];
    const float* Wih2   = (const float*)d_in[9];
    const float* Whh2   = (const float*)d_in[10];
    const float* bih2   = (const float*)d_in[11];
    const float* bhh2   = (const float*)d_in[12];
    const float* Wq     = (const float*)d_in[13];
    const float* bq     = (const float*)d_in[14];
    const float* Wout   = (const float*)d_in[15];
    const float* bout   = (const float*)d_in[16];
    float* out = (float*)d_out;

    char* ws = (char*)d_ws;
    _Float16* WoutH = (_Float16*)(ws + OFF_WOUT);
    _Float16* W1h   = (_Float16*)(ws + OFF_W1H);
    _Float16* W2h   = (_Float16*)(ws + OFF_W2H);
    _Float16* Wqh   = (_Float16*)(ws + OFF_WQH);
    float*    bias1 = (float*)(ws + OFF_B1);
    float*    bias2 = (float*)(ws + OFF_B2);
    _Float16* h2ctx = (_Float16*)(ws + OFF_H2CTX);

    k_cvt_f16<<<dim3((VOCAB * EMB + 255) / 256), dim3(256), 0, stream>>>(Wout, WoutH, VOCAB * EMB);
    k_cvt_f16<<<dim3(16), dim3(256), 0, stream>>>(Wq, Wqh, QD * H2D);
    k_prep_w1<<<dim3(512), dim3(320), 0, stream>>>(Wih1, Whh1, bih1, bhh1, W1h, bias1);
    k_prep_w2<<<dim3(256), dim3(192), 0, stream>>>(Wih2, Whh2, bih2, bhh2, W2h, bias2);

    k_recurrent<<<dim3(BDIM), dim3(1024), 0, stream>>>(
        key, values, mask, text, emb, W1h, bias1, W2h, bias2, Wqh, bq, h2ctx);

    k_outproj<<<dim3((VOCAB + 63) / 64, (BDIM * LSTEPS) / 64), dim3(256), 0, stream>>>(
        h2ctx, WoutH, bout, out);
}

// Round 3
// 867.082 us; speedup vs baseline: 1.7757x; 1.7757x over previous
//
#include <hip/hip_runtime.h>
#include <hip/hip_bf16.h>
#include <hip/hip_fp16.h>

#define VOCAB 5000
#define EMB 128
#define H1D 128
#define H2D 64
#define QD 64
#define TDIM 256
#define BDIM 512
#define LTEXT 30
#define LSTEPS 29

typedef __attribute__((ext_vector_type(4))) float f32x4;
typedef __attribute__((ext_vector_type(8))) _Float16 f16x8;
typedef __attribute__((ext_vector_type(2))) _Float16 h2v;

// ---- workspace layout (bytes) ----
#define OFF_WOUT  0u                    // 5000*128 fp16 = 1,280,000
#define OFF_W1H   0x140000u             // 512*320 fp16  =   327,680
#define OFF_W2H   (OFF_W1H + 512u*320u*2u)
#define OFF_WQH   (OFF_W2H + 256u*192u*2u)
#define OFF_B1    (OFF_WQH + 64u*64u*2u)
#define OFF_B2    (OFF_B1 + 512u*4u)
#define OFF_H2CTX 0x1B0000u             // 14848*128 fp16 = 3,801,088

__device__ __forceinline__ float sigmoidf_(float x) {
    return __builtin_amdgcn_rcpf(1.0f + __expf(-x));
}

__device__ __forceinline__ float tanh_fast(float x) {
    float e = __expf(2.0f * x);
    return 1.0f - 2.0f * __builtin_amdgcn_rcpf(e + 1.0f);
}

__device__ __forceinline__ float dot8(f16x8 w, f16x8 u, float acc) {
    union U8 { f16x8 v; h2v h[4]; };
    U8 W; W.v = w; U8 X; X.v = u;
#if __has_builtin(__builtin_amdgcn_fdot2)
    acc = __builtin_amdgcn_fdot2(W.h[0], X.h[0], acc, false);
    acc = __builtin_amdgcn_fdot2(W.h[1], X.h[1], acc, false);
    acc = __builtin_amdgcn_fdot2(W.h[2], X.h[2], acc, false);
    acc = __builtin_amdgcn_fdot2(W.h[3], X.h[3], acc, false);
#else
    #pragma unroll
    for (int i = 0; i < 8; ++i) acc += (float)w[i] * (float)u[i];
#endif
    return acc;
}

// Pin 4 dwords in arch VGPRs (blocks remat-as-reload; allocator still owns them).
__device__ __forceinline__ f16x8 load_pin(const f16x8* p) {
    union WU { f16x8 h; float f[4]; } u;
    u.h = *p;
    asm volatile("" : "+v"(u.f[0]), "+v"(u.f[1]), "+v"(u.f[2]), "+v"(u.f[3]));
    return u.h;
}

// ---------------------------------------------------------------------------
// Prep kernels (unchanged).
// ---------------------------------------------------------------------------
__global__ void k_cvt_f16(const float* __restrict__ W, _Float16* __restrict__ Wh, int n) {
    int i = blockIdx.x * 256 + threadIdx.x;
    if (i < n) Wh[i] = (_Float16)W[i];
}

__global__ void k_prep_w1(const float* __restrict__ Wih1, const float* __restrict__ Whh1,
                          const float* __restrict__ bih1, const float* __restrict__ bhh1,
                          _Float16* __restrict__ W1h, float* __restrict__ bias1) {
    int g = blockIdx.x;          // 512
    int k = threadIdx.x;         // 320
    float v = (k < 192) ? Wih1[g * 192 + k] : Whh1[g * 128 + (k - 192)];
    W1h[g * 320 + k] = (_Float16)v;
    if (k == 0) bias1[g] = bih1[g] + bhh1[g];
}

__global__ void k_prep_w2(const float* __restrict__ Wih2, const float* __restrict__ Whh2,
                          const float* __restrict__ bih2, const float* __restrict__ bhh2,
                          _Float16* __restrict__ W2h, float* __restrict__ bias2) {
    int g = blockIdx.x;          // 256
    int k = threadIdx.x;         // 192
    float v = (k < 128) ? Wih2[g * 128 + k] : Whh2[g * 64 + (k - 128)];
    W2h[g * 192 + k] = (_Float16)v;
    if (k == 0) bias2[g] = bih2[g] + bhh2[g];
}

// ---------------------------------------------------------------------------
// Kernel A v5: 256 blocks x 1024 threads, 2 rows/block, 1 block/CU (16 waves).
//  - launch_bounds(1024,4) -> 128-VGPR cap; W1 half-rows pinned (80 VGPR)
//  - W2 streamed from L2 each step via laundered pointer (no LICM blowup)
//  - key slot-major (conflict-free), valT swizzled v^(s>>2) (balanced banks)
//  - c1/c2/biases/mask in registers; emb prefetched one step ahead
// ---------------------------------------------------------------------------
__global__ __launch_bounds__(1024, 4) void k_recurrent(
    const float* __restrict__ key, const float* __restrict__ values,
    const float* __restrict__ mask, const int* __restrict__ text,
    const float* __restrict__ emb,
    const _Float16* __restrict__ W1h, const float* __restrict__ bias1,
    const _Float16* __restrict__ W2h, const float* __restrict__ bias2,
    const _Float16* __restrict__ Wqh, const float* __restrict__ bq,
    _Float16* __restrict__ h2ctx)
{
    __shared__ alignas(16) _Float16 s_key[2][8][256][8];   // 64 KB [r][k>>3][t][k&7]
    __shared__ alignas(16) _Float16 s_valT[2][32][64][8];  // 64 KB [r][s=t>>3][k^(t>>5)][t&7]
    __shared__ alignas(16) _Float16 s_Wq[8][64][8];        // 8 KB  [c][qj][.]
    __shared__ alignas(16) _Float16 s_u16[2][384];         // [x128|ctx64|h1 128|h2 64]
    __shared__ alignas(16) _Float16 s_q16[2][64];
    __shared__ alignas(16) _Float16 s_ma16[2][256];
    __shared__ float s_g1[2][512];
    __shared__ float s_g2[2][256];
    __shared__ float s_redM[8], s_redA[8], s_redB[8];
    __shared__ int   s_tok[2][LSTEPS];

    const int tid = threadIdx.x;
    const int b0 = blockIdx.x * 2;

    const int g1gate = tid >> 1, g1half = tid & 1;
    const int g2gate = tid >> 2, g2q = tid & 3;

    // ---- W1 half-row into pinned registers (80 VGPR) ----
    f16x8 w1h[20];
    {
        const f16x8* p = (const f16x8*)(W1h + (size_t)g1gate * 320 + g1half * 160);
        #pragma unroll
        for (int c = 0; c < 20; ++c) w1h[c] = load_pin(p + c);
    }
    float b1r = (g1half == 0) ? bias1[g1gate] : 0.f;
    float b2r = (g2q == 0) ? bias2[g2gate] : 0.f;
    const float bqr  = (tid < 128) ? bq[tid & 63] : 0.f;
    const float mreg = (tid < 512) ? mask[(size_t)(b0 + (tid >> 8)) * TDIM + (tid & 255)] : 0.f;

    // ---- one-time preload ----
    if (tid < 64) {
        int r = tid >> 5, tt = tid & 31;
        if (tt < LSTEPS) s_tok[r][tt] = text[(b0 + r) * LTEXT + tt];
    }
    if (tid < 256) {                                        // x for t=0
        int r = tid >> 7, k = tid & 127;
        s_u16[r][k] = (_Float16)emb[(size_t)text[(b0 + r) * LTEXT] * EMB + k];
    }
    if (tid < 512) {                                        // ctx,h1,h2 = 0
        int r = tid >> 8, idx = tid & 255;
        s_u16[r][128 + idx] = (_Float16)0.f;
    }
    if (tid < 512) {                                        // Wq slot-major
        int qj = tid >> 3, c = tid & 7;
        f16x8 w = *(const f16x8*)(Wqh + (qj << 6) + (c << 3));
        *(f16x8*)&s_Wq[c][qj][0] = w;
    }
    // key/values -> LDS fp16 (one wave loads one (r,t) stripe; coalesced)
    {
        const int r = tid >> 9;
        const int tw = (tid >> 6) & 7;
        const int k = tid & 63;
        #pragma unroll 4
        for (int it = 0; it < 32; ++it) {
            int t = tw + (it << 3);
            size_t g = ((size_t)t * BDIM + b0 + r) * QD + k;
            float kf = key[g];
            float vf = values[g];
            s_key[r][k >> 3][t][k & 7] = (_Float16)kf;
            s_valT[r][t >> 3][k ^ (t >> 5)][t & 7] = (_Float16)vf;
        }
    }

    float c1reg = 0.f;   // tid<256: c1[r=tid>>7][j=tid&127]
    float c2reg = 0.f;   // tid<128: c2[r=tid>>6][j=tid&63]
    __syncthreads();

    #pragma unroll 1
    for (int t = 0; t < LSTEPS; ++t) {
        // issue next-step embedding load early (write late)
        float xpref = 0.f;
        const int pr = tid >> 7, pk = tid & 127;
        const bool havepref = (t + 1 < LSTEPS) && (tid < 256);
        if (havepref) xpref = emb[(size_t)s_tok[pr][t + 1] * EMB + pk];

        // ---- g1: (gate, half) x 2 rows; W1 in VGPRs, u broadcast from LDS ----
        {
            const f16x8* up0 = (const f16x8*)&s_u16[0][g1half * 160];
            const f16x8* up1 = (const f16x8*)&s_u16[1][g1half * 160];
            float a0 = b1r, a1 = b1r;
            #pragma unroll
            for (int c = 0; c < 20; ++c) {
                f16x8 w = w1h[c];
                a0 = dot8(w, up0[c], a0);
                a1 = dot8(w, up1[c], a1);
            }
            a0 += __shfl_down(a0, 1);
            a1 += __shfl_down(a1, 1);
            if (g1half == 0) { s_g1[0][g1gate] = a0; s_g1[1][g1gate] = a1; }
        }
        __syncthreads();                                   // B1

        // ---- W2 quarter-row loads issue here (hide under LSTM1) ----
        f16x8 w2r[6];
        {
            union PU { const f16x8* p; unsigned u[2]; } wp;
            wp.p = (const f16x8*)(W2h + (size_t)g2gate * 192 + (size_t)g2q * 48);
            asm volatile("" : "+v"(wp.u[0]), "+v"(wp.u[1]));  // defeat LICM
            #pragma unroll
            for (int c = 0; c < 6; ++c) w2r[c] = wp.p[c];
        }

        // ---- LSTM1 (2 x 128 units), c1 in register ----
        if (tid < 256) {
            int r = tid >> 7, j = tid & 127;
            float gi = s_g1[r][j], gf = s_g1[r][128 + j];
            float gg = s_g1[r][256 + j], go = s_g1[r][384 + j];
            float c = sigmoidf_(gf) * c1reg + sigmoidf_(gi) * tanh_fast(gg);
            c1reg = c;
            float h = sigmoidf_(go) * tanh_fast(c);
            s_u16[r][192 + j] = (_Float16)h;
        }
        __syncthreads();                                   // B2

        // ---- g2: (gate, quarter) x 2 rows ----
        {
            const f16x8* v0 = (const f16x8*)&s_u16[0][192 + g2q * 48];
            const f16x8* v1 = (const f16x8*)&s_u16[1][192 + g2q * 48];
            float p0 = b2r, p1 = b2r;
            #pragma unroll
            for (int c = 0; c < 6; ++c) {
                f16x8 w = w2r[c];
                p0 = dot8(w, v0[c], p0);
                p1 = dot8(w, v1[c], p1);
            }
            p0 += __shfl_down(p0, 1);
            p0 += __shfl_down(p0, 2);
            p1 += __shfl_down(p1, 1);
            p1 += __shfl_down(p1, 2);
            if (g2q == 0) { s_g2[0][g2gate] = p0; s_g2[1][g2gate] = p1; }
        }
        __syncthreads();                                   // B3

        // ---- LSTM2 (2 x 64 units), c2 in register; store h2 ----
        if (tid < 128) {
            int r = tid >> 6, j = tid & 63;
            float gi = s_g2[r][j], gf = s_g2[r][64 + j];
            float gg = s_g2[r][128 + j], go = s_g2[r][192 + j];
            float c = sigmoidf_(gf) * c2reg + sigmoidf_(gi) * tanh_fast(gg);
            c2reg = c;
            float h = sigmoidf_(go) * tanh_fast(c);
            s_u16[r][320 + j] = (_Float16)h;
            h2ctx[((size_t)(b0 + r) * LSTEPS + t) * 128 + j] = (_Float16)h;
        }
        __syncthreads();                                   // B4

        // ---- q = Wq @ h2 + bq (slot-major LDS, conflict-free) ----
        if (tid < 128) {
            int r = tid >> 6, qj = tid & 63;
            const f16x8* hv = (const f16x8*)&s_u16[r][320];
            float a = bqr;
            #pragma unroll
            for (int c = 0; c < 8; ++c) {
                f16x8 w = *(const f16x8*)&s_Wq[c][qj][0];
                a = dot8(w, hv[c], a);
            }
            s_q16[r][qj] = (_Float16)a;
        }
        __syncthreads();                                   // B5

        // ---- energy + per-wave softmax partials ----
        const int row = tid >> 8, tk = tid & 255;
        float e = 0.f, mw = 0.f, pexp = 0.f;
        if (tid < 512) {
            const f16x8* qv = (const f16x8*)&s_q16[row][0];
            #pragma unroll
            for (int j = 0; j < 8; ++j) {
                f16x8 kk = *(const f16x8*)&s_key[row][j][tk][0];
                e = dot8(kk, qv[j], e);
            }
            float m = e;
            #pragma unroll
            for (int off = 1; off < 64; off <<= 1) m = fmaxf(m, __shfl_xor(m, off));
            mw = m;
            pexp = __expf(e - mw);
            float mp = mreg * pexp;
            float sp = pexp, smp = mp;
            #pragma unroll
            for (int off = 1; off < 64; off <<= 1) {
                sp += __shfl_xor(sp, off);
                smp += __shfl_xor(smp, off);
            }
            if ((tid & 63) == 0) {
                int w = tid >> 6;
                s_redM[w] = mw; s_redA[w] = sp; s_redB[w] = smp;
            }
        }
        __syncthreads();                                   // B6

        if (tid < 512) {
            int base = row * 4;
            float m = fmaxf(fmaxf(s_redM[base], s_redM[base + 1]),
                            fmaxf(s_redM[base + 2], s_redM[base + 3]));
            float S1 = 0.f, S2 = 0.f;
            #pragma unroll
            for (int w = 0; w < 4; ++w) {
                float sc = __expf(s_redM[base + w] - m);
                S1 += s_redA[base + w] * sc;
                S2 += s_redB[base + w] * sc;
            }
            float scale = __expf(mw - m);
            float mp = mreg * pexp * scale;
            float denom = fmaxf(S2, 2e-30f * S1);
            s_ma16[row][tk] = (_Float16)(mp * __builtin_amdgcn_rcpf(denom));
        }
        __syncthreads();                                   // B7

        // ---- ctx: (row=tid>>9, v=(tid>>3)&63, ch=tid&7), 8-lane shuffle combine ----
        {
            const int crow = tid >> 9, v = (tid >> 3) & 63, ch = tid & 7;
            float cacc = 0.f;
            #pragma unroll
            for (int j = 0; j < 4; ++j) {
                int s = (ch << 2) + j;
                f16x8 vv = *(const f16x8*)&s_valT[crow][s][v ^ ch][0];
                f16x8 ma = *(const f16x8*)&s_ma16[crow][s << 3];
                cacc = dot8(vv, ma, cacc);
            }
            cacc += __shfl_down(cacc, 1);
            cacc += __shfl_down(cacc, 2);
            cacc += __shfl_down(cacc, 4);
            if (havepref) s_u16[pr][pk] = (_Float16)xpref;  // next-step x (g1 done at B1)
            if (ch == 0) {
                s_u16[crow][128 + v] = (_Float16)cacc;
                h2ctx[((size_t)(b0 + crow) * LSTEPS + t) * 128 + 64 + v] = (_Float16)cacc;
            }
        }
        __syncthreads();                                   // B8
    }
}

// ---------------------------------------------------------------------------
// Kernel B: out = h2ctx @ W_out^T + b_out, fp16 MFMA 16x16x32. (unchanged)
// ---------------------------------------------------------------------------
#define KP 136

__global__ __launch_bounds__(256, 4) void k_outproj(
    const _Float16* __restrict__ A,
    const _Float16* __restrict__ Bw,
    const float* __restrict__ b_out,
    float* __restrict__ out)
{
    __shared__ _Float16 As[64 * KP];
    __shared__ _Float16 Bs[64 * KP];
    const int tid = threadIdx.x;
    const int m0 = blockIdx.y * 64;
    const int v0 = blockIdx.x * 64;

    const uint4* Ag = (const uint4*)(A + (size_t)m0 * 128);
    uint4* AsU = (uint4*)As;
    #pragma unroll
    for (int i = 0; i < 4; ++i) {
        int fi = tid + 256 * i;
        int r = fi >> 4, c = fi & 15;
        AsU[r * 17 + c] = Ag[fi];
    }
    const uint4* Bg = (const uint4*)Bw;
    uint4* BsU = (uint4*)Bs;
    #pragma unroll
    for (int i = 0; i < 4; ++i) {
        int fi = tid + 256 * i;
        int r = fi >> 4, c = fi & 15;
        int v = v0 + r;
        uint4 val = make_uint4(0u, 0u, 0u, 0u);
        if (v < VOCAB) val = Bg[(size_t)v * 16 + c];
        BsU[r * 17 + c] = val;
    }
    __syncthreads();

    const int wv = tid >> 6, lane = tid & 63;
    const int fm = lane & 15, quad = lane >> 4;

    f32x4 acc[4];
    #pragma unroll
    for (int nt = 0; nt < 4; ++nt) acc[nt] = (f32x4){0.f, 0.f, 0.f, 0.f};

    #pragma unroll
    for (int kt = 0; kt < 4; ++kt) {
        f16x8 af = *(const f16x8*)&As[(16 * wv + fm) * KP + kt * 32 + quad * 8];
        #pragma unroll
        for (int nt = 0; nt < 4; ++nt) {
            f16x8 bf = *(const f16x8*)&Bs[(nt * 16 + fm) * KP + kt * 32 + quad * 8];
            acc[nt] = __builtin_amdgcn_mfma_f32_16x16x32_f16(bf, af, acc[nt], 0, 0, 0);
        }
    }

    const int rowm = m0 + 16 * wv + fm;
    #pragma unroll
    for (int nt = 0; nt < 4; ++nt) {
        int vb = v0 + nt * 16 + quad * 4;
        if (vb + 3 < VOCAB) {
            float4 bo = *(const float4*)&b_out[vb];
            float4 res;
            res.x = acc[nt][0] + bo.x;
            res.y = acc[nt][1] + bo.y;
            res.z = acc[nt][2] + bo.z;
            res.w = acc[nt][3] + bo.w;
            *(float4*)&out[(size_t)rowm * VOCAB + vb] = res;
        } else {
            #pragma unroll
            for (int r = 0; r < 4; ++r) {
                int v = vb + r;
                if (v < VOCAB) out[(size_t)rowm * VOCAB + v] = acc[nt][r] + b_out[v];
            }
        }
    }
}

extern "C" void kernel_launch(void* const* d_in, const int* in_sizes, int n_in,
                              void* d_out, int out_size, void* d_ws, size_t ws_size,
                              hipStream_t stream) {
    const float* key    = (const float*)d_in[0];
    const float* values = (const float*)d_in[1];
    const float* mask   = (const float*)d_in[2];
    const int*   text   = (const int*)d_in[3];
    const float* emb    = (const float*)d_in[4];
    const float* Wih1   = (const float*)d_in[5];
    const float* Whh1   = (const float*)d_in[6];
    const float* bih1   = (const float*)d_in[7];
    const float* bhh1   = (const float*)d_in[8];
    const float* Wih2   = (const float*)d_in[9];
    const float* Whh2   = (const float*)d_in[10];
    const float* bih2   = (const float*)d_in[11];
    const float* bhh2   = (const float*)d_in[12];
    const float* Wq     = (const float*)d_in[13];
    const float* bq     = (const float*)d_in[14];
    const float* Wout   = (const float*)d_in[15];
    const float* bout   = (const float*)d_in[16];
    float* out = (float*)d_out;

    char* ws = (char*)d_ws;
    _Float16* WoutH = (_Float16*)(ws + OFF_WOUT);
    _Float16* W1h   = (_Float16*)(ws + OFF_W1H);
    _Float16* W2h   = (_Float16*)(ws + OFF_W2H);
    _Float16* Wqh   = (_Float16*)(ws + OFF_WQH);
    float*    bias1 = (float*)(ws + OFF_B1);
    float*    bias2 = (float*)(ws + OFF_B2);
    _Float16* h2ctx = (_Float16*)(ws + OFF_H2CTX);

    k_cvt_f16<<<dim3((VOCAB * EMB + 255) / 256), dim3(256), 0, stream>>>(Wout, WoutH, VOCAB * EMB);
    k_cvt_f16<<<dim3(16), dim3(256), 0, stream>>>(Wq, Wqh, QD * H2D);
    k_prep_w1<<<dim3(512), dim3(320), 0, stream>>>(Wih1, Whh1, bih1, bhh1, W1h, bias1);
    k_prep_w2<<<dim3(256), dim3(192), 0, stream>>>(Wih2, Whh2, bih2, bhh2, W2h, bias2);

    k_recurrent<<<dim3(BDIM / 2), dim3(1024), 0, stream>>>(
        key, values, mask, text, emb, W1h, bias1, W2h, bias2, Wqh, bq, h2ctx);

    k_outproj<<<dim3((VOCAB + 63) / 64, (BDIM * LSTEPS) / 64), dim3(256), 0, stream>>>(
        h2ctx, WoutH, bout, out);
}

// Round 4
// 862.205 us; speedup vs baseline: 1.7858x; 1.0057x over previous
//
#include <hip/hip_runtime.h>
#include <hip/hip_bf16.h>
#include <hip/hip_fp16.h>

#define VOCAB 5000
#define EMB 128
#define H1D 128
#define H2D 64
#define QD 64
#define TDIM 256
#define BDIM 512
#define LTEXT 30
#define LSTEPS 29

typedef __attribute__((ext_vector_type(4))) float f32x4;
typedef __attribute__((ext_vector_type(8))) _Float16 f16x8;
typedef __attribute__((ext_vector_type(2))) _Float16 h2v;

// ---- workspace layout (bytes) ----
#define OFF_WOUT  0u                    // 5000*128 fp16 = 1,280,000
#define OFF_W1H   0x140000u             // 512*320 fp16  =   327,680
#define OFF_W2H   (OFF_W1H + 512u*320u*2u)
#define OFF_WQH   (OFF_W2H + 256u*192u*2u)
#define OFF_B1    (OFF_WQH + 64u*64u*2u)
#define OFF_B2    (OFF_B1 + 512u*4u)
#define OFF_H2CTX 0x1B0000u             // 14848*128 fp16 = 3,801,088

__device__ __forceinline__ float sigmoidf_(float x) {
    return __builtin_amdgcn_rcpf(1.0f + __expf(-x));
}

__device__ __forceinline__ float tanh_fast(float x) {
    float e = __expf(2.0f * x);
    return 1.0f - 2.0f * __builtin_amdgcn_rcpf(e + 1.0f);
}

__device__ __forceinline__ float dot8(f16x8 w, f16x8 u, float acc) {
    union U8 { f16x8 v; h2v h[4]; };
    U8 W; W.v = w; U8 X; X.v = u;
#if __has_builtin(__builtin_amdgcn_fdot2)
    acc = __builtin_amdgcn_fdot2(W.h[0], X.h[0], acc, false);
    acc = __builtin_amdgcn_fdot2(W.h[1], X.h[1], acc, false);
    acc = __builtin_amdgcn_fdot2(W.h[2], X.h[2], acc, false);
    acc = __builtin_amdgcn_fdot2(W.h[3], X.h[3], acc, false);
#else
    #pragma unroll
    for (int i = 0; i < 8; ++i) acc += (float)w[i] * (float)u[i];
#endif
    return acc;
}

// Pin 4 dwords in arch VGPRs (blocks remat-as-reload; allocator still owns them).
__device__ __forceinline__ f16x8 load_pin(const f16x8* p) {
    union WU { f16x8 h; float f[4]; } u;
    u.h = *p;
    asm volatile("" : "+v"(u.f[0]), "+v"(u.f[1]), "+v"(u.f[2]), "+v"(u.f[3]));
    return u.h;
}

// ---------------------------------------------------------------------------
// Prep kernels (unchanged).
// ---------------------------------------------------------------------------
__global__ void k_cvt_f16(const float* __restrict__ W, _Float16* __restrict__ Wh, int n) {
    int i = blockIdx.x * 256 + threadIdx.x;
    if (i < n) Wh[i] = (_Float16)W[i];
}

__global__ void k_prep_w1(const float* __restrict__ Wih1, const float* __restrict__ Whh1,
                          const float* __restrict__ bih1, const float* __restrict__ bhh1,
                          _Float16* __restrict__ W1h, float* __restrict__ bias1) {
    int g = blockIdx.x;          // 512
    int k = threadIdx.x;         // 320
    float v = (k < 192) ? Wih1[g * 192 + k] : Whh1[g * 128 + (k - 192)];
    W1h[g * 320 + k] = (_Float16)v;
    if (k == 0) bias1[g] = bih1[g] + bhh1[g];
}

__global__ void k_prep_w2(const float* __restrict__ Wih2, const float* __restrict__ Whh2,
                          const float* __restrict__ bih2, const float* __restrict__ bhh2,
                          _Float16* __restrict__ W2h, float* __restrict__ bias2) {
    int g = blockIdx.x;          // 256
    int k = threadIdx.x;         // 192
    float v = (k < 128) ? Wih2[g * 128 + k] : Whh2[g * 64 + (k - 128)];
    W2h[g * 192 + k] = (_Float16)v;
    if (k == 0) bias2[g] = bih2[g] + bhh2[g];
}

// ---------------------------------------------------------------------------
// Kernel A v6: 256 blocks x 1024 threads, 2 rows/block, 1 block/CU (16 waves).
//  - amdgpu_waves_per_eu(4,4): FORCE the 128-VGPR budget (launch_bounds'
//    min-waves form let the allocator pick 64 and spill the pinned W1)
//  - W1 half-rows pinned in VGPRs (80); W2 streamed from L2 per step
//  - key slot-major (conflict-free); valT chunk decomposition s=j*8+ch so
//    the ma16 chunk reads hit 8 distinct bank-groups (was 4-way conflict)
// ---------------------------------------------------------------------------
__global__ __attribute__((amdgpu_flat_work_group_size(1024, 1024), amdgpu_waves_per_eu(4, 4)))
void k_recurrent(
    const float* __restrict__ key, const float* __restrict__ values,
    const float* __restrict__ mask, const int* __restrict__ text,
    const float* __restrict__ emb,
    const _Float16* __restrict__ W1h, const float* __restrict__ bias1,
    const _Float16* __restrict__ W2h, const float* __restrict__ bias2,
    const _Float16* __restrict__ Wqh, const float* __restrict__ bq,
    _Float16* __restrict__ h2ctx)
{
    __shared__ alignas(16) _Float16 s_key[2][8][256][8];   // 64 KB [r][k>>3][t][k&7]
    __shared__ alignas(16) _Float16 s_valT[2][32][64][8];  // 64 KB [r][s=t>>3][k^(s&7)][t&7]
    __shared__ alignas(16) _Float16 s_Wq[8][64][8];        // 8 KB  [c][qj][.]
    __shared__ alignas(16) _Float16 s_u16[2][384];         // [x128|ctx64|h1 128|h2 64]
    __shared__ alignas(16) _Float16 s_q16[2][64];
    __shared__ alignas(16) _Float16 s_ma16[2][256];
    __shared__ float s_g1[2][512];
    __shared__ float s_g2[2][256];
    __shared__ float s_redM[8], s_redA[8], s_redB[8];
    __shared__ int   s_tok[2][LSTEPS];

    const int tid = threadIdx.x;
    const int b0 = blockIdx.x * 2;

    const int g1gate = tid >> 1, g1half = tid & 1;
    const int g2gate = tid >> 2, g2q = tid & 3;

    // ---- W1 half-row into pinned registers (80 VGPR) ----
    f16x8 w1h[20];
    {
        const f16x8* p = (const f16x8*)(W1h + (size_t)g1gate * 320 + g1half * 160);
        #pragma unroll
        for (int c = 0; c < 20; ++c) w1h[c] = load_pin(p + c);
    }
    float b1r = (g1half == 0) ? bias1[g1gate] : 0.f;
    float b2r = (g2q == 0) ? bias2[g2gate] : 0.f;
    const float bqr  = (tid < 128) ? bq[tid & 63] : 0.f;
    const float mreg = (tid < 512) ? mask[(size_t)(b0 + (tid >> 8)) * TDIM + (tid & 255)] : 0.f;

    // ---- one-time preload ----
    if (tid < 64) {
        int r = tid >> 5, tt = tid & 31;
        if (tt < LSTEPS) s_tok[r][tt] = text[(b0 + r) * LTEXT + tt];
    }
    if (tid < 256) {                                        // x for t=0
        int r = tid >> 7, k = tid & 127;
        s_u16[r][k] = (_Float16)emb[(size_t)text[(b0 + r) * LTEXT] * EMB + k];
    }
    if (tid < 512) {                                        // ctx,h1,h2 = 0
        int r = tid >> 8, idx = tid & 255;
        s_u16[r][128 + idx] = (_Float16)0.f;
    }
    if (tid < 512) {                                        // Wq slot-major
        int qj = tid >> 3, c = tid & 7;
        f16x8 w = *(const f16x8*)(Wqh + (qj << 6) + (c << 3));
        *(f16x8*)&s_Wq[c][qj][0] = w;
    }
    // key/values -> LDS fp16 (one wave loads one (r,t) stripe; coalesced)
    {
        const int r = tid >> 9;
        const int tw = (tid >> 6) & 7;
        const int k = tid & 63;
        #pragma unroll 4
        for (int it = 0; it < 32; ++it) {
            int t = tw + (it << 3);
            size_t g = ((size_t)t * BDIM + b0 + r) * QD + k;
            float kf = key[g];
            float vf = values[g];
            s_key[r][k >> 3][t][k & 7] = (_Float16)kf;
            s_valT[r][t >> 3][k ^ ((t >> 3) & 7)][t & 7] = (_Float16)vf;
        }
    }

    float c1reg = 0.f;   // tid<256: c1[r=tid>>7][j=tid&127]
    float c2reg = 0.f;   // tid<128: c2[r=tid>>6][j=tid&63]
    __syncthreads();

    #pragma unroll 1
    for (int t = 0; t < LSTEPS; ++t) {
        // issue next-step embedding load early (write late)
        float xpref = 0.f;
        const int pr = tid >> 7, pk = tid & 127;
        const bool havepref = (t + 1 < LSTEPS) && (tid < 256);
        if (havepref) xpref = emb[(size_t)s_tok[pr][t + 1] * EMB + pk];

        // ---- g1: (gate, half) x 2 rows; W1 in VGPRs, u broadcast from LDS ----
        {
            const f16x8* up0 = (const f16x8*)&s_u16[0][g1half * 160];
            const f16x8* up1 = (const f16x8*)&s_u16[1][g1half * 160];
            float a0 = b1r, a1 = b1r;
            #pragma unroll
            for (int c = 0; c < 20; ++c) {
                f16x8 w = w1h[c];
                a0 = dot8(w, up0[c], a0);
                a1 = dot8(w, up1[c], a1);
            }
            a0 += __shfl_down(a0, 1);
            a1 += __shfl_down(a1, 1);
            if (g1half == 0) { s_g1[0][g1gate] = a0; s_g1[1][g1gate] = a1; }
        }
        __syncthreads();                                   // B1

        // ---- W2 quarter-row loads issue here (hide under LSTM1) ----
        f16x8 w2r[6];
        {
            union PU { const f16x8* p; unsigned u[2]; } wp;
            wp.p = (const f16x8*)(W2h + (size_t)g2gate * 192 + (size_t)g2q * 48);
            asm volatile("" : "+v"(wp.u[0]), "+v"(wp.u[1]));  // defeat LICM
            #pragma unroll
            for (int c = 0; c < 6; ++c) w2r[c] = wp.p[c];
        }

        // ---- LSTM1 (2 x 128 units), c1 in register ----
        if (tid < 256) {
            int r = tid >> 7, j = tid & 127;
            float gi = s_g1[r][j], gf = s_g1[r][128 + j];
            float gg = s_g1[r][256 + j], go = s_g1[r][384 + j];
            float c = sigmoidf_(gf) * c1reg + sigmoidf_(gi) * tanh_fast(gg);
            c1reg = c;
            float h = sigmoidf_(go) * tanh_fast(c);
            s_u16[r][192 + j] = (_Float16)h;
        }
        __syncthreads();                                   // B2

        // ---- g2: (gate, quarter) x 2 rows ----
        {
            const f16x8* v0 = (const f16x8*)&s_u16[0][192 + g2q * 48];
            const f16x8* v1 = (const f16x8*)&s_u16[1][192 + g2q * 48];
            float p0 = b2r, p1 = b2r;
            #pragma unroll
            for (int c = 0; c < 6; ++c) {
                f16x8 w = w2r[c];
                p0 = dot8(w, v0[c], p0);
                p1 = dot8(w, v1[c], p1);
            }
            p0 += __shfl_down(p0, 1);
            p0 += __shfl_down(p0, 2);
            p1 += __shfl_down(p1, 1);
            p1 += __shfl_down(p1, 2);
            if (g2q == 0) { s_g2[0][g2gate] = p0; s_g2[1][g2gate] = p1; }
        }
        __syncthreads();                                   // B3

        // ---- LSTM2 (2 x 64 units), c2 in register; store h2 ----
        if (tid < 128) {
            int r = tid >> 6, j = tid & 63;
            float gi = s_g2[r][j], gf = s_g2[r][64 + j];
            float gg = s_g2[r][128 + j], go = s_g2[r][192 + j];
            float c = sigmoidf_(gf) * c2reg + sigmoidf_(gi) * tanh_fast(gg);
            c2reg = c;
            float h = sigmoidf_(go) * tanh_fast(c);
            s_u16[r][320 + j] = (_Float16)h;
            h2ctx[((size_t)(b0 + r) * LSTEPS + t) * 128 + j] = (_Float16)h;
        }
        __syncthreads();                                   // B4

        // ---- q = Wq @ h2 + bq (slot-major LDS, conflict-free) ----
        if (tid < 128) {
            int r = tid >> 6, qj = tid & 63;
            const f16x8* hv = (const f16x8*)&s_u16[r][320];
            float a = bqr;
            #pragma unroll
            for (int c = 0; c < 8; ++c) {
                f16x8 w = *(const f16x8*)&s_Wq[c][qj][0];
                a = dot8(w, hv[c], a);
            }
            s_q16[r][qj] = (_Float16)a;
        }
        __syncthreads();                                   // B5

        // ---- energy + per-wave softmax partials ----
        const int row = tid >> 8, tk = tid & 255;
        float e = 0.f, mw = 0.f, pexp = 0.f;
        if (tid < 512) {
            const f16x8* qv = (const f16x8*)&s_q16[row][0];
            #pragma unroll
            for (int j = 0; j < 8; ++j) {
                f16x8 kk = *(const f16x8*)&s_key[row][j][tk][0];
                e = dot8(kk, qv[j], e);
            }
            float m = e;
            #pragma unroll
            for (int off = 1; off < 64; off <<= 1) m = fmaxf(m, __shfl_xor(m, off));
            mw = m;
            pexp = __expf(e - mw);
            float mp = mreg * pexp;
            float sp = pexp, smp = mp;
            #pragma unroll
            for (int off = 1; off < 64; off <<= 1) {
                sp += __shfl_xor(sp, off);
                smp += __shfl_xor(smp, off);
            }
            if ((tid & 63) == 0) {
                int w = tid >> 6;
                s_redM[w] = mw; s_redA[w] = sp; s_redB[w] = smp;
            }
        }
        __syncthreads();                                   // B6

        if (tid < 512) {
            int base = row * 4;
            float m = fmaxf(fmaxf(s_redM[base], s_redM[base + 1]),
                            fmaxf(s_redM[base + 2], s_redM[base + 3]));
            float S1 = 0.f, S2 = 0.f;
            #pragma unroll
            for (int w = 0; w < 4; ++w) {
                float sc = __expf(s_redM[base + w] - m);
                S1 += s_redA[base + w] * sc;
                S2 += s_redB[base + w] * sc;
            }
            float scale = __expf(mw - m);
            float mp = mreg * pexp * scale;
            float denom = fmaxf(S2, 2e-30f * S1);
            s_ma16[row][tk] = (_Float16)(mp * __builtin_amdgcn_rcpf(denom));
        }
        __syncthreads();                                   // B7

        // ---- ctx: (crow=tid>>9, v=(tid>>3)&63, ch=tid&7); chunks s=j*8+ch ----
        {
            const int crow = tid >> 9, v = (tid >> 3) & 63, ch = tid & 7;
            float cacc = 0.f;
            #pragma unroll
            for (int j = 0; j < 4; ++j) {
                int s = (j << 3) + ch;                      // s&7 == ch
                f16x8 vv = *(const f16x8*)&s_valT[crow][s][v ^ ch][0];
                f16x8 ma = *(const f16x8*)&s_ma16[crow][s << 3];
                cacc = dot8(vv, ma, cacc);
            }
            cacc += __shfl_down(cacc, 1);
            cacc += __shfl_down(cacc, 2);
            cacc += __shfl_down(cacc, 4);
            if (havepref) s_u16[pr][pk] = (_Float16)xpref;  // next-step x (g1 done at B1)
            if (ch == 0) {
                s_u16[crow][128 + v] = (_Float16)cacc;
                h2ctx[((size_t)(b0 + crow) * LSTEPS + t) * 128 + 64 + v] = (_Float16)cacc;
            }
        }
        __syncthreads();                                   // B8
    }
}

// ---------------------------------------------------------------------------
// Kernel B: out = h2ctx @ W_out^T + b_out, fp16 MFMA 16x16x32. (unchanged)
// ---------------------------------------------------------------------------
#define KP 136

__global__ __launch_bounds__(256, 4) void k_outproj(
    const _Float16* __restrict__ A,
    const _Float16* __restrict__ Bw,
    const float* __restrict__ b_out,
    float* __restrict__ out)
{
    __shared__ _Float16 As[64 * KP];
    __shared__ _Float16 Bs[64 * KP];
    const int tid = threadIdx.x;
    const int m0 = blockIdx.y * 64;
    const int v0 = blockIdx.x * 64;

    const uint4* Ag = (const uint4*)(A + (size_t)m0 * 128);
    uint4* AsU = (uint4*)As;
    #pragma unroll
    for (int i = 0; i < 4; ++i) {
        int fi = tid + 256 * i;
        int r = fi >> 4, c = fi & 15;
        AsU[r * 17 + c] = Ag[fi];
    }
    const uint4* Bg = (const uint4*)Bw;
    uint4* BsU = (uint4*)Bs;
    #pragma unroll
    for (int i = 0; i < 4; ++i) {
        int fi = tid + 256 * i;
        int r = fi >> 4, c = fi & 15;
        int v = v0 + r;
        uint4 val = make_uint4(0u, 0u, 0u, 0u);
        if (v < VOCAB) val = Bg[(size_t)v * 16 + c];
        BsU[r * 17 + c] = val;
    }
    __syncthreads();

    const int wv = tid >> 6, lane = tid & 63;
    const int fm = lane & 15, quad = lane >> 4;

    f32x4 acc[4];
    #pragma unroll
    for (int nt = 0; nt < 4; ++nt) acc[nt] = (f32x4){0.f, 0.f, 0.f, 0.f};

    #pragma unroll
    for (int kt = 0; kt < 4; ++kt) {
        f16x8 af = *(const f16x8*)&As[(16 * wv + fm) * KP + kt * 32 + quad * 8];
        #pragma unroll
        for (int nt = 0; nt < 4; ++nt) {
            f16x8 bf = *(const f16x8*)&Bs[(nt * 16 + fm) * KP + kt * 32 + quad * 8];
            acc[nt] = __builtin_amdgcn_mfma_f32_16x16x32_f16(bf, af, acc[nt], 0, 0, 0);
        }
    }

    const int rowm = m0 + 16 * wv + fm;
    #pragma unroll
    for (int nt = 0; nt < 4; ++nt) {
        int vb = v0 + nt * 16 + quad * 4;
        if (vb + 3 < VOCAB) {
            float4 bo = *(const float4*)&b_out[vb];
            float4 res;
            res.x = acc[nt][0] + bo.x;
            res.y = acc[nt][1] + bo.y;
            res.z = acc[nt][2] + bo.z;
            res.w = acc[nt][3] + bo.w;
            *(float4*)&out[(size_t)rowm * VOCAB + vb] = res;
        } else {
            #pragma unroll
            for (int r = 0; r < 4; ++r) {
                int v = vb + r;
                if (v < VOCAB) out[(size_t)rowm * VOCAB + v] = acc[nt][r] + b_out[v];
            }
        }
    }
}

extern "C" void kernel_launch(void* const* d_in, const int* in_sizes, int n_in,
                              void* d_out, int out_size, void* d_ws, size_t ws_size,
                              hipStream_t stream) {
    const float* key    = (const float*)d_in[0];
    const float* values = (const float*)d_in[1];
    const float* mask   = (const float*)d_in[2];
    const int*   text   = (const int*)d_in[3];
    const float* emb    = (const float*)d_in[4];
    const float* Wih1   = (const float*)d_in[5];
    const float* Whh1   = (const float*)d_in[6];
    const float* bih1   = (const float*)d_in[7];
    const float* bhh1   = (const float*)d_in[8];
    const float* Wih2   = (const float*)d_in[9];
    const float* Whh2   = (const float*)d_in[10];
    const float* bih2   = (const float*)d_in[11];
    const float* bhh2   = (const float*)d_in[12];
    const float* Wq     = (const float*)d_in[13];
    const float* bq     = (const float*)d_in[14];
    const float* Wout   = (const float*)d_in[15];
    const float* bout   = (const float*)d_in[16];
    float* out = (float*)d_out;

    char* ws = (char*)d_ws;
    _Float16* WoutH = (_Float16*)(ws + OFF_WOUT);
    _Float16* W1h   = (_Float16*)(ws + OFF_W1H);
    _Float16* W2h   = (_Float16*)(ws + OFF_W2H);
    _Float16* Wqh   = (_Float16*)(ws + OFF_WQH);
    float*    bias1 = (float*)(ws + OFF_B1);
    float*    bias2 = (float*)(ws + OFF_B2);
    _Float16* h2ctx = (_Float16*)(ws + OFF_H2CTX);

    k_cvt_f16<<<dim3((VOCAB * EMB + 255) / 256), dim3(256), 0, stream>>>(Wout, WoutH, VOCAB * EMB);
    k_cvt_f16<<<dim3(16), dim3(256), 0, stream>>>(Wq, Wqh, QD * H2D);
    k_prep_w1<<<dim3(512), dim3(320), 0, stream>>>(Wih1, Whh1, bih1, bhh1, W1h, bias1);
    k_prep_w2<<<dim3(256), dim3(192), 0, stream>>>(Wih2, Whh2, bih2, bhh2, W2h, bias2);

    k_recurrent<<<dim3(BDIM / 2), dim3(1024), 0, stream>>>(
        key, values, mask, text, emb, W1h, bias1, W2h, bias2, Wqh, bq, h2ctx);

    k_outproj<<<dim3((VOCAB + 63) / 64, (BDIM * LSTEPS) / 64), dim3(256), 0, stream>>>(
        h2ctx, WoutH, bout, out);
}